// Round 14
// baseline (99.205 us; speedup 1.0000x reference)
//
#include <hip/hip_runtime.h>
#include <hip/hip_bf16.h>
#include <math.h>

#define BN_EPS 1e-5f
#define B_  96
#define N_  20
#define D_  2048
#define K_  10
#define M_  (B_*N_)   // 1920
#define R_  (2*D_)    // 4096

typedef __attribute__((ext_vector_type(8))) short bf16x8;
typedef __attribute__((ext_vector_type(4))) float f32x4;
typedef __attribute__((ext_vector_type(8))) unsigned short ushort8;

static __device__ __forceinline__ unsigned short f2bf(float f) {
  unsigned int u = __builtin_bit_cast(unsigned int, f);
  u = u + 0x7fffu + ((u >> 16) & 1u);   // RNE (finite inputs only)
  return (unsigned short)(u >> 16);
}

#define GLOAD_LDS16(g, l) \
  __builtin_amdgcn_global_load_lds((const __attribute__((address_space(1))) void*)(g), \
                                   (__attribute__((address_space(3))) void*)(l), 16, 0, 0)

// ------- kernel 1: wide prep -----------------------------------------------
// Round-14 restructure: knn's 96 monolithic blocks (20 us serial critical
// path, pinned non-GEMM at ~31-33 us for 7 rounds) are split into 1920
// independent (b,n) WAVE tasks across 240 blocks; Gram rows go to ws (innr_g).
// Blocks 240..751: flat chunk space for cast_x (linear) + cast_w (repack).
// Top-k moves to a tiny follow-up kernel.
__global__ __launch_bounds__(512, 2) void prep1_kernel(const float* __restrict__ x,
                                                       const float* __restrict__ cw,
                                                       float* __restrict__ innr_g,
                                                       unsigned short* __restrict__ Xb,
                                                       unsigned short* __restrict__ Wn)
{
  int t = threadIdx.x;
  if (blockIdx.x >= 240) {
    // ---- cast blocks: 1,540,096 chunks of 8 elements, grid-stride ----
    // i < 491520: cast_x (x is [96][20][2048] contiguous -> pure linear cast)
    // else: cast_w chunk j=i-491520: Wn[r][k], r=2*o+h (h=0 lo-half, h=1 hi-half)
    for (int i = (blockIdx.x - 240)*512 + t; i < 1540096; i += 512*512) {
      if (i < 491520) {
        const float* src = x + (size_t)i * 8;
        float4 a = *(const float4*)src, c = *(const float4*)(src + 4);
        ushort8 o = { f2bf(a.x), f2bf(a.y), f2bf(a.z), f2bf(a.w),
                      f2bf(c.x), f2bf(c.y), f2bf(c.z), f2bf(c.w) };
        *((ushort8*)Xb + i) = o;
      } else {
        int j = i - 491520;
        int r = j >> 8, k = (j & 255) * 8;
        const float* src = cw + (size_t)(r >> 1) * R_ + ((r & 1) << 11) + k;
        float4 a = *(const float4*)src, c = *(const float4*)(src + 4);
        ushort8 o = { f2bf(a.x), f2bf(a.y), f2bf(a.z), f2bf(a.w),
                      f2bf(c.x), f2bf(c.y), f2bf(c.z), f2bf(c.w) };
        *((ushort8*)Wn + j) = o;
      }
    }
    return;
  }
  // ---- Gram dot blocks: wave task = (b, n); compute innr[n][m] for m>=n ----
  int w = t >> 6, lane = t & 63;
  int task = blockIdx.x * 8 + w;                 // 240*8 = 1920 exactly
  int b = task / N_, n = task % N_;
  const float* xb = x + (size_t)b * N_ * D_;
  const float4* pn = (const float4*)(xb + n * D_);
  float4 c[8];
  #pragma unroll
  for (int j = 0; j < 8; ++j) c[j] = pn[lane + 64*j];
  float* ig = innr_g + b * (N_*N_);
  for (int m = n; m < N_; ++m) {
    const float4* pm = (const float4*)(xb + m * D_);
    float s0 = 0.f, s1 = 0.f, s2 = 0.f, s3 = 0.f;
    #pragma unroll
    for (int j = 0; j < 8; ++j) {
      float4 v = pm[lane + 64*j];
      float d = fmaf(c[j].x, v.x, fmaf(c[j].y, v.y,
                fmaf(c[j].z, v.z, c[j].w * v.w)));
      if      ((j&3)==0) s0 += d;
      else if ((j&3)==1) s1 += d;
      else if ((j&3)==2) s2 += d;
      else               s3 += d;
    }
    float s = (s0 + s1) + (s2 + s3);
    #pragma unroll
    for (int off = 32; off > 0; off >>= 1)
      s += __shfl_xor(s, off, 64);
    if (lane == 0) { ig[n*N_ + m] = s; ig[m*N_ + n] = s; }
  }
}

// ------- kernel 2: top-k selection (per batch, 1 wave) ---------------------
__global__ __launch_bounds__(64) void topk_kernel(const float* __restrict__ innr_g,
                                                  int* __restrict__ nn_idx)
{
  int b = blockIdx.x, t = threadIdx.x;
  __shared__ float adjl[N_*N_];
  const float* ig = innr_g + b * (N_*N_);
  for (int p = t; p < N_*N_; p += 64) {
    int n = p / N_, m = p % N_;
    adjl[p] = ig[n*N_+n] + ig[m*N_+m] - 2.f * ig[p];
  }
  __syncthreads();
  if (t < N_) {
    int n = t;
    unsigned mask = 0;
    for (int it = 0; it < K_; ++it) {
      float bv = INFINITY; int bi = 0;
      for (int m = 0; m < N_; ++m) {
        if (!((mask >> m) & 1u)) {
          float v = adjl[n*N_+m];
          if (v < bv) { bv = v; bi = m; }
        }
      }
      mask |= 1u << bi;
      nn_idx[(b*N_ + n)*K_ + it] = bi;
    }
  }
}

// ---------------- kernel 3: fused bf16 MFMA GEMM + BN/ReLU/neighbor-max ----
// EXACT round-11 structure (proven 44.1 us): 80x128 tile, BK=64 (3-bit XOR
// swizzle), 4 waves, grid 24x32=768, 2-phase A+B LDS double-buffer at
// 3 blocks/CU (LDS exactly 53248 B; idxl loaded post-K-loop into dead Bs1).
// Round-12 (counted vmcnt) and round-13 (B-to-reg) both failed to beat it.
__global__ __launch_bounds__(256, 3) void fused_gemm(
    const unsigned short* __restrict__ Xb, const unsigned short* __restrict__ Wn,
    const int* __restrict__ nn_idx, const float* __restrict__ conv_b,
    const float* __restrict__ gamma, const float* __restrict__ beta,
    const float* __restrict__ mean, const float* __restrict__ var,
    float* __restrict__ out)
{
  __shared__ __align__(16) char smem[53248];
  // buffer sel at smem + sel*26624: As [80][64] 10240 B, Bs [128][64] 16384 B
  float* Cl  = (float*)smem;                    // [80][128] f32, 40960 B (epilogue reuse)
  int*   idxl = (int*)(smem + 40960);           // [4][200] int, 3200 B — loaded POST-K-loop

  // bijective XCD-chunk swizzle (768 % 8 == 0)
  int flat = blockIdx.y * 24 + blockIdx.x;
  int nf = (flat & 7) * 96 + (flat >> 3);
  int bx = nf % 24, by = nf / 24;

  int t = threadIdx.x, lane = t & 63, w = t >> 6;  // w = wr (0..3)
  int m0 = bx * 80, b0 = bx * 4;
  int r0 = by * 128, o0 = by * 64;
  int rowsel = lane & 15, ksel = lane >> 4;

  f32x4 acc[5][2] = {};

  auto stage = [&](int sel, int k0) {
    unsigned short* Asb = (unsigned short*)(smem + sel*26624);
    unsigned short* Bsb = (unsigned short*)(smem + sel*26624 + 10240);
    #pragma unroll
    for (int i = 0; i < 3; ++i) {                 // A: 80*8 = 640 16B-chunks
      int fl = i*256 + t;
      if (fl < 640) {
        int row = fl >> 3, kc = fl & 7;
        GLOAD_LDS16(Xb + (size_t)(m0 + row) * D_ + k0 + ((kc ^ (row & 7)) << 3),
                    Asb + fl*8);
      }
    }
    #pragma unroll
    for (int i = 0; i < 4; ++i) {                 // B: 128*8 = 1024 16B-chunks
      int fl = i*256 + t;
      int row = fl >> 3, kc = fl & 7;
      GLOAD_LDS16(Wn + (size_t)(r0 + row) * D_ + k0 + ((kc ^ (row & 7)) << 3),
                  Bsb + fl*8);
    }
  };

  auto compute = [&](int sel) {
    unsigned short* Asb = (unsigned short*)(smem + sel*26624);
    unsigned short* Bsb = (unsigned short*)(smem + sel*26624 + 10240);
    #pragma unroll
    for (int ks = 0; ks < 2; ++ks) {
      int swz = ((ks*4 + ksel) ^ (rowsel & 7)) << 3;   // tile offsets are 16-mult
      bf16x8 a[5], bfr[2];
      #pragma unroll
      for (int mi = 0; mi < 5; ++mi)
        a[mi] = *(const bf16x8*)(Asb + (mi*16 + rowsel)*64 + swz);
      #pragma unroll
      for (int ri = 0; ri < 2; ++ri)
        bfr[ri] = *(const bf16x8*)(Bsb + (w*32 + ri*16 + rowsel)*64 + swz);
      #pragma unroll
      for (int mi = 0; mi < 5; ++mi)
        #pragma unroll
        for (int ri = 0; ri < 2; ++ri)
          acc[mi][ri] = __builtin_amdgcn_mfma_f32_16x16x32_bf16(a[mi], bfr[ri], acc[mi][ri], 0, 0, 0);
    }
  };

  stage(0, 0);
  for (int kt = 0; kt < D_/64; ++kt) {
    __syncthreads();                              // drains stage issued last step
    if (kt + 1 < D_/64) stage((kt+1) & 1, (kt+1)*64);
    compute(kt & 1);
  }
  __syncthreads();                                // all buffer reads done

  // ---- fused epilogue ----
  #pragma unroll
  for (int mi = 0; mi < 5; ++mi)
    #pragma unroll
    for (int ri = 0; ri < 2; ++ri)
      #pragma unroll
      for (int rg = 0; rg < 4; ++rg)
        Cl[(mi*16 + ksel*4 + rg)*128 + w*32 + ri*16 + rowsel] = acc[mi][ri][rg];
  for (int i = t; i < 4*N_*K_; i += 256) idxl[i] = nn_idx[b0*N_*K_ + i];
  __syncthreads();

  int bb = w, oo = lane;               // (batch-in-tile, output-in-tile)
  int og = o0 + oo;
  float invv  = gamma[og] / sqrtf(var[og] + BN_EPS);
  float shift = fmaf(-mean[og], invv, beta[og]);
  float bias  = conv_b[og];
  float best = 0.f;                    // relu identity
  int rbase = bb * N_;
  for (int n = 0; n < N_; ++n) {
    float Pv = Cl[(rbase + n)*128 + oo*2];
    float Qn = Cl[(rbase + n)*128 + oo*2 + 1];
    float aa = Pv - Qn + bias;
    const int* ix = idxl + bb*N_*K_ + n*K_;
    #pragma unroll
    for (int kk = 0; kk < K_; ++kk) {
      int j = ix[kk];
      float v = fmaf(aa + Cl[(rbase + j)*128 + oo*2 + 1], invv, shift);
      best = fmaxf(best, v);
    }
  }
  out[(size_t)(b0 + bb) * D_ + og] = best;
}

extern "C" void kernel_launch(void* const* d_in, const int* in_sizes, int n_in,
                              void* d_out, int out_size, void* d_ws, size_t ws_size,
                              hipStream_t stream)
{
  const float* x      = (const float*)d_in[0];
  const float* conv_w = (const float*)d_in[1];
  const float* conv_b = (const float*)d_in[2];
  const float* gamma  = (const float*)d_in[3];
  const float* beta   = (const float*)d_in[4];
  const float* mean   = (const float*)d_in[5];
  const float* var    = (const float*)d_in[6];

  // workspace: nn_idx 76800 | Xb 7864320 | Wn 16777216 | innr_g 153600  (24.87 MB)
  int* nn_idx = (int*)d_ws;
  unsigned short* Xb = (unsigned short*)((char*)d_ws + 76800);
  unsigned short* Wn = (unsigned short*)((char*)d_ws + 76800 + (size_t)M_*D_*2);
  float* innr_g = (float*)((char*)d_ws + 76800 + (size_t)M_*D_*2 + (size_t)R_*D_*2);

  prep1_kernel<<<752, 512, 0, stream>>>(x, conv_w, innr_g, Xb, Wn);
  topk_kernel<<<B_, 64, 0, stream>>>(innr_g, nn_idx);
  fused_gemm<<<dim3(24, 32), 256, 0, stream>>>(
      Xb, Wn, nn_idx, conv_b, gamma, beta, mean, var, (float*)d_out);
}

// Round 15
// 92.396 us; speedup vs baseline: 1.0737x; 1.0737x over previous
//
#include <hip/hip_runtime.h>
#include <hip/hip_bf16.h>
#include <math.h>

#define BN_EPS 1e-5f
#define B_  96
#define N_  20
#define D_  2048
#define K_  10
#define M_  (B_*N_)   // 1920
#define R_  (2*D_)    // 4096

typedef __attribute__((ext_vector_type(8))) short bf16x8;
typedef __attribute__((ext_vector_type(4))) float f32x4;
typedef __attribute__((ext_vector_type(8))) unsigned short ushort8;

static __device__ __forceinline__ unsigned short f2bf(float f) {
  unsigned int u = __builtin_bit_cast(unsigned int, f);
  u = u + 0x7fffu + ((u >> 16) & 1u);   // RNE (finite inputs only)
  return (unsigned short)(u >> 16);
}

#define GLOAD_LDS16(g, l) \
  __builtin_amdgcn_global_load_lds((const __attribute__((address_space(1))) void*)(g), \
                                   (__attribute__((address_space(3))) void*)(l), 16, 0, 0)

// ------- kernel 1: Gram dots — 1920 independent (b,n) wave tasks ----------
__global__ __launch_bounds__(512) void gram_kernel(const float* __restrict__ x,
                                                   float* __restrict__ innr_g)
{
  int t = threadIdx.x, w = t >> 6, lane = t & 63;
  int task = blockIdx.x * 8 + w;                 // 240*8 = 1920 exactly
  int b = task / N_, n = task % N_;
  const float* xb = x + (size_t)b * N_ * D_;
  const float4* pn = (const float4*)(xb + n * D_);
  float4 c[8];
  #pragma unroll
  for (int j = 0; j < 8; ++j) c[j] = pn[lane + 64*j];
  float* ig = innr_g + b * (N_*N_);
  for (int m = n; m < N_; ++m) {
    const float4* pm = (const float4*)(xb + m * D_);
    float s0 = 0.f, s1 = 0.f, s2 = 0.f, s3 = 0.f;
    #pragma unroll
    for (int j = 0; j < 8; ++j) {
      float4 v = pm[lane + 64*j];
      float d = fmaf(c[j].x, v.x, fmaf(c[j].y, v.y,
                fmaf(c[j].z, v.z, c[j].w * v.w)));
      if      ((j&3)==0) s0 += d;
      else if ((j&3)==1) s1 += d;
      else if ((j&3)==2) s2 += d;
      else               s3 += d;
    }
    float s = (s0 + s1) + (s2 + s3);
    #pragma unroll
    for (int off = 32; off > 0; off >>= 1)
      s += __shfl_xor(s, off, 64);
    if (lane == 0) { ig[n*N_ + m] = s; ig[m*N_ + n] = s; }
  }
}

// ------- kernel 2: top-k selection (per batch, 1 wave) ---------------------
__global__ __launch_bounds__(64) void topk_kernel(const float* __restrict__ innr_g,
                                                  int* __restrict__ nn_idx)
{
  int b = blockIdx.x, t = threadIdx.x;
  __shared__ float adjl[N_*N_];
  const float* ig = innr_g + b * (N_*N_);
  for (int p = t; p < N_*N_; p += 64) {
    int n = p / N_, m = p % N_;
    adjl[p] = ig[n*N_+n] + ig[m*N_+m] - 2.f * ig[p];
  }
  __syncthreads();
  if (t < N_) {
    int n = t;
    unsigned mask = 0;
    for (int it = 0; it < K_; ++it) {
      float bv = INFINITY; int bi = 0;
      for (int m = 0; m < N_; ++m) {
        if (!((mask >> m) & 1u)) {
          float v = adjl[n*N_+m];
          if (v < bv) { bv = v; bi = m; }
        }
      }
      mask |= 1u << bi;
      nn_idx[(b*N_ + n)*K_ + it] = bi;
    }
  }
}

// ------- kernel 3: casts — exact 4-chunk-per-thread ILP --------------------
// Combined chunk space: i < 491520 -> cast_x (linear); else cast_w repack
// (Wn[r][k], r=2*o+h: h=0 -> cw[o][k], h=1 -> cw[o][2048+k]).
// 752 blocks * 512 threads * 4 chunks = 1,540,096 exact. All 8 float4 loads
// issue before any store (round-14 lesson: grid-stride 1-chunk loop was
// latency-serial at 1.6 TB/s).
__global__ __launch_bounds__(512) void cast_kernel(const float* __restrict__ x,
                                                   const float* __restrict__ cw,
                                                   unsigned short* __restrict__ Xb,
                                                   unsigned short* __restrict__ Wn)
{
  int q = blockIdx.x * 512 + threadIdx.x;        // 0..385023
  const float* sp[4];
  ushort8* dp[4];
  #pragma unroll
  for (int s = 0; s < 4; ++s) {
    int i = q + s * 385024;
    if (i < 491520) {
      sp[s] = x + (size_t)i * 8;
      dp[s] = (ushort8*)Xb + i;
    } else {
      int j = i - 491520;
      int r = j >> 8, k = (j & 255) * 8;
      sp[s] = cw + (size_t)(r >> 1) * R_ + ((r & 1) << 11) + k;
      dp[s] = (ushort8*)Wn + j;
    }
  }
  float4 a[4], c[4];
  #pragma unroll
  for (int s = 0; s < 4; ++s) { a[s] = *(const float4*)sp[s]; c[s] = *(const float4*)(sp[s] + 4); }
  #pragma unroll
  for (int s = 0; s < 4; ++s) {
    ushort8 o = { f2bf(a[s].x), f2bf(a[s].y), f2bf(a[s].z), f2bf(a[s].w),
                  f2bf(c[s].x), f2bf(c[s].y), f2bf(c[s].z), f2bf(c[s].w) };
    *dp[s] = o;
  }
}

// ---------------- kernel 4: fused bf16 MFMA GEMM + BN/ReLU/neighbor-max ----
// EXACT round-11 structure (proven 44.1 us): 80x128 tile, BK=64 (3-bit XOR
// swizzle), 4 waves, grid 24x32=768, 2-phase A+B LDS double-buffer at
// 3 blocks/CU (LDS exactly 53248 B; idxl loaded post-K-loop into dead Bs1).
__global__ __launch_bounds__(256, 3) void fused_gemm(
    const unsigned short* __restrict__ Xb, const unsigned short* __restrict__ Wn,
    const int* __restrict__ nn_idx, const float* __restrict__ conv_b,
    const float* __restrict__ gamma, const float* __restrict__ beta,
    const float* __restrict__ mean, const float* __restrict__ var,
    float* __restrict__ out)
{
  __shared__ __align__(16) char smem[53248];
  float* Cl  = (float*)smem;                    // [80][128] f32, 40960 B (epilogue reuse)
  int*   idxl = (int*)(smem + 40960);           // [4][200] int, 3200 B — loaded POST-K-loop

  // bijective XCD-chunk swizzle (768 % 8 == 0)
  int flat = blockIdx.y * 24 + blockIdx.x;
  int nf = (flat & 7) * 96 + (flat >> 3);
  int bx = nf % 24, by = nf / 24;

  int t = threadIdx.x, lane = t & 63, w = t >> 6;  // w = wr (0..3)
  int m0 = bx * 80, b0 = bx * 4;
  int r0 = by * 128, o0 = by * 64;
  int rowsel = lane & 15, ksel = lane >> 4;

  f32x4 acc[5][2] = {};

  auto stage = [&](int sel, int k0) {
    unsigned short* Asb = (unsigned short*)(smem + sel*26624);
    unsigned short* Bsb = (unsigned short*)(smem + sel*26624 + 10240);
    #pragma unroll
    for (int i = 0; i < 3; ++i) {                 // A: 80*8 = 640 16B-chunks
      int fl = i*256 + t;
      if (fl < 640) {
        int row = fl >> 3, kc = fl & 7;
        GLOAD_LDS16(Xb + (size_t)(m0 + row) * D_ + k0 + ((kc ^ (row & 7)) << 3),
                    Asb + fl*8);
      }
    }
    #pragma unroll
    for (int i = 0; i < 4; ++i) {                 // B: 128*8 = 1024 16B-chunks
      int fl = i*256 + t;
      int row = fl >> 3, kc = fl & 7;
      GLOAD_LDS16(Wn + (size_t)(r0 + row) * D_ + k0 + ((kc ^ (row & 7)) << 3),
                  Bsb + fl*8);
    }
  };

  auto compute = [&](int sel) {
    unsigned short* Asb = (unsigned short*)(smem + sel*26624);
    unsigned short* Bsb = (unsigned short*)(smem + sel*26624 + 10240);
    #pragma unroll
    for (int ks = 0; ks < 2; ++ks) {
      int swz = ((ks*4 + ksel) ^ (rowsel & 7)) << 3;   // tile offsets are 16-mult
      bf16x8 a[5], bfr[2];
      #pragma unroll
      for (int mi = 0; mi < 5; ++mi)
        a[mi] = *(const bf16x8*)(Asb + (mi*16 + rowsel)*64 + swz);
      #pragma unroll
      for (int ri = 0; ri < 2; ++ri)
        bfr[ri] = *(const bf16x8*)(Bsb + (w*32 + ri*16 + rowsel)*64 + swz);
      #pragma unroll
      for (int mi = 0; mi < 5; ++mi)
        #pragma unroll
        for (int ri = 0; ri < 2; ++ri)
          acc[mi][ri] = __builtin_amdgcn_mfma_f32_16x16x32_bf16(a[mi], bfr[ri], acc[mi][ri], 0, 0, 0);
    }
  };

  stage(0, 0);
  for (int kt = 0; kt < D_/64; ++kt) {
    __syncthreads();                              // drains stage issued last step
    if (kt + 1 < D_/64) stage((kt+1) & 1, (kt+1)*64);
    compute(kt & 1);
  }
  __syncthreads();                                // all buffer reads done

  // ---- fused epilogue ----
  #pragma unroll
  for (int mi = 0; mi < 5; ++mi)
    #pragma unroll
    for (int ri = 0; ri < 2; ++ri)
      #pragma unroll
      for (int rg = 0; rg < 4; ++rg)
        Cl[(mi*16 + ksel*4 + rg)*128 + w*32 + ri*16 + rowsel] = acc[mi][ri][rg];
  for (int i = t; i < 4*N_*K_; i += 256) idxl[i] = nn_idx[b0*N_*K_ + i];
  __syncthreads();

  int bb = w, oo = lane;               // (batch-in-tile, output-in-tile)
  int og = o0 + oo;
  float invv  = gamma[og] / sqrtf(var[og] + BN_EPS);
  float shift = fmaf(-mean[og], invv, beta[og]);
  float bias  = conv_b[og];
  float best = 0.f;                    // relu identity
  int rbase = bb * N_;
  for (int n = 0; n < N_; ++n) {
    float Pv = Cl[(rbase + n)*128 + oo*2];
    float Qn = Cl[(rbase + n)*128 + oo*2 + 1];
    float aa = Pv - Qn + bias;
    const int* ix = idxl + bb*N_*K_ + n*K_;
    #pragma unroll
    for (int kk = 0; kk < K_; ++kk) {
      int j = ix[kk];
      float v = fmaf(aa + Cl[(rbase + j)*128 + oo*2 + 1], invv, shift);
      best = fmaxf(best, v);
    }
  }
  out[(size_t)(b0 + bb) * D_ + og] = best;
}

extern "C" void kernel_launch(void* const* d_in, const int* in_sizes, int n_in,
                              void* d_out, int out_size, void* d_ws, size_t ws_size,
                              hipStream_t stream)
{
  const float* x      = (const float*)d_in[0];
  const float* conv_w = (const float*)d_in[1];
  const float* conv_b = (const float*)d_in[2];
  const float* gamma  = (const float*)d_in[3];
  const float* beta   = (const float*)d_in[4];
  const float* mean   = (const float*)d_in[5];
  const float* var    = (const float*)d_in[6];

  // workspace: nn_idx 76800 | Xb 7864320 | Wn 16777216 | innr_g 153600  (24.87 MB)
  int* nn_idx = (int*)d_ws;
  unsigned short* Xb = (unsigned short*)((char*)d_ws + 76800);
  unsigned short* Wn = (unsigned short*)((char*)d_ws + 76800 + (size_t)M_*D_*2);
  float* innr_g = (float*)((char*)d_ws + 76800 + (size_t)M_*D_*2 + (size_t)R_*D_*2);

  gram_kernel<<<240, 512, 0, stream>>>(x, innr_g);
  topk_kernel<<<B_, 64, 0, stream>>>(innr_g, nn_idx);
  cast_kernel<<<752, 512, 0, stream>>>(x, conv_w, Xb, Wn);
  fused_gemm<<<dim3(24, 32), 256, 0, stream>>>(
      Xb, Wn, nn_idx, conv_b, gamma, beta, mean, var, (float*)d_out);
}